// Round 14
// baseline (500.313 us; speedup 1.0000x reference)
//
#include <hip/hip_runtime.h>
#include <cstddef>

// ---------------------------------------------------------------------------
// embed+concat -> Linear(80->96) -> 3x SAGEConv(96, mean) -> MLP(96->256->256->1)
// fp32 in/out. N = in_sizes[1], E = in_sizes[2]/2.
// Round 13 (resubmit, unmeasured): T14 async-STAGE split in gemm_mfma — issue
// step k+1's global loads right after the LDS-ready barrier so they fly under
// step k's MFMAs. Everything else identical to round 12.
// ---------------------------------------------------------------------------

#define NB 256

using f16x4 = __attribute__((ext_vector_type(4))) _Float16;
using f32x4 = __attribute__((ext_vector_type(4))) float;

// ---- CSR: count in-degree --------------------------------------------------
__global__ __launch_bounds__(NB) void count_int_kernel(const int* __restrict__ dst,
                                                       int* __restrict__ cnt, int E) {
    int e = blockIdx.x * NB + threadIdx.x;
    if (e < E) atomicAdd(&cnt[dst[e]], 1);
}

// ---- multi-block scan, stage 1: per-block (2048 elems) sums ----------------
__global__ __launch_bounds__(NB) void scan_part1(const int* __restrict__ cnt,
                                                 int* __restrict__ part, int n) {
    __shared__ int ws[4];
    const int tid = threadIdx.x;
    const int base = blockIdx.x * 2048 + tid * 8;
    int s = 0;
#pragma unroll
    for (int q = 0; q < 8; ++q) {
        int i = base + q;
        if (i < n) s += cnt[i];
    }
#pragma unroll
    for (int off = 1; off < 64; off <<= 1) s += __shfl_xor(s, off);
    if ((tid & 63) == 0) ws[tid >> 6] = s;
    __syncthreads();
    if (tid == 0) part[blockIdx.x] = ws[0] + ws[1] + ws[2] + ws[3];
}

// ---- stage 2: single-wave exclusive scan of partials (nb <= 64) ------------
__global__ __launch_bounds__(64) void scan_part2(int* __restrict__ part,
                                                 int* __restrict__ rowptr,
                                                 int nb, int n) {
    const int lane = threadIdx.x;
    int v = (lane < nb) ? part[lane] : 0;
    int incl = v;
#pragma unroll
    for (int off = 1; off < 64; off <<= 1) {
        int u = __shfl_up(incl, off);
        if (lane >= off) incl += u;
    }
    if (lane < nb) part[lane] = incl - v;
    if (lane == 63) rowptr[n] = incl;
}

// ---- stage 3: per-block local scan + global offset -> rowptr & cursor ------
__global__ __launch_bounds__(NB) void scan_part3(const int* __restrict__ cnt,
                                                 const int* __restrict__ part,
                                                 int* __restrict__ rowptr,
                                                 int* __restrict__ cursor, int n) {
    __shared__ int ws[4];
    const int tid = threadIdx.x;
    const int lane = tid & 63, w = tid >> 6;
    const int base = blockIdx.x * 2048 + tid * 8;
    int loc[8];
    int s = 0;
#pragma unroll
    for (int q = 0; q < 8; ++q) {
        int i = base + q;
        int v = (i < n) ? cnt[i] : 0;
        loc[q] = s;
        s += v;
    }
    int incl = s;
#pragma unroll
    for (int off = 1; off < 64; off <<= 1) {
        int u = __shfl_up(incl, off);
        if (lane >= off) incl += u;
    }
    if (lane == 63) ws[w] = incl;
    __syncthreads();
    int woff = 0;
    for (int i = 0; i < w; ++i) woff += ws[i];
    int gbase = part[blockIdx.x] + woff + (incl - s);
#pragma unroll
    for (int q = 0; q < 8; ++q) {
        int i = base + q;
        if (i < n) {
            int v = gbase + loc[q];
            rowptr[i] = v;
            cursor[i] = v;
        }
    }
}

// ---- CSR: fill column (src) list -------------------------------------------
__global__ __launch_bounds__(NB) void fill_csr_kernel(const int* __restrict__ src,
                                                      const int* __restrict__ dst,
                                                      int* __restrict__ cursor,
                                                      int* __restrict__ col, int E) {
    int e = blockIdx.x * NB + threadIdx.x;
    if (e >= E) return;
    int p = atomicAdd(&cursor[dst[e]], 1);
    col[p] = src[e];
}

// ---- gather-mean: G[n] = mean_{j in col[rowptr[n]:rowptr[n+1]]} X[j] -------
__global__ __launch_bounds__(NB) void gather_mean_kernel(
    const float* __restrict__ X, const int* __restrict__ rowptr,
    const int* __restrict__ col, float* __restrict__ G, int N) {
    int idx = blockIdx.x * NB + threadIdx.x;
    int node = idx / 24;
    if (node >= N) return;
    int c = idx - node * 24;
    const int s = rowptr[node], pe = rowptr[node + 1];
    float4 acc = {0.f, 0.f, 0.f, 0.f};
    int p = s;
    for (; p + 3 < pe; p += 4) {
        int j0 = col[p], j1 = col[p + 1], j2 = col[p + 2], j3 = col[p + 3];
        float4 v0 = *reinterpret_cast<const float4*>(&X[(size_t)j0 * 96 + 4 * c]);
        float4 v1 = *reinterpret_cast<const float4*>(&X[(size_t)j1 * 96 + 4 * c]);
        float4 v2 = *reinterpret_cast<const float4*>(&X[(size_t)j2 * 96 + 4 * c]);
        float4 v3 = *reinterpret_cast<const float4*>(&X[(size_t)j3 * 96 + 4 * c]);
        acc.x += (v0.x + v1.x) + (v2.x + v3.x);
        acc.y += (v0.y + v1.y) + (v2.y + v3.y);
        acc.z += (v0.z + v1.z) + (v2.z + v3.z);
        acc.w += (v0.w + v1.w) + (v2.w + v3.w);
    }
    for (; p < pe; ++p) {
        int j = col[p];
        float4 v = *reinterpret_cast<const float4*>(&X[(size_t)j * 96 + 4 * c]);
        acc.x += v.x; acc.y += v.y; acc.z += v.z; acc.w += v.w;
    }
    int deg = pe - s;
    float inv = (deg > 0) ? 1.f / (float)deg : 0.f;
    acc.x *= inv; acc.y *= inv; acc.z *= inv; acc.w *= inv;
    *reinterpret_cast<float4*>(&G[(size_t)node * 96 + 4 * c]) = acc;
}

// ---- fp32 -> (hi, lo) f16 split --------------------------------------------
__device__ inline void cvt_split(float4 f, f16x4& hi, f16x4& lo) {
    _Float16 h0 = (_Float16)f.x, h1 = (_Float16)f.y;
    _Float16 h2 = (_Float16)f.z, h3 = (_Float16)f.w;
    hi = (f16x4){h0, h1, h2, h3};
    lo = (f16x4){(_Float16)(f.x - (float)h0), (_Float16)(f.y - (float)h1),
                 (_Float16)(f.z - (float)h2), (_Float16)(f.w - (float)h3)};
}

// ---- MFMA GEMM with T14 async-STAGE split ----------------------------------
// fp16-split: acc += Ahi*Bhi + Ahi*Blo + Alo*Bhi (lo*lo dropped).
// Pipeline per k-step: [barrier] write regs->LDS, [barrier], ISSUE k+1 global
// loads (fly under MFMA), MFMA phase. v_mfma_f32_16x16x16f16 layouts as r11.
template <int K, int OUT, int TC, int BK, bool RELU, bool SAGE, bool EMB, bool FDOT>
__global__ __launch_bounds__(NB) void gemm_mfma(
    const float* __restrict__ X, const float* __restrict__ G,
    const float* __restrict__ Wx, const float* __restrict__ Wg,
    const float* __restrict__ bias,
    const int* __restrict__ xl, const int* __restrict__ xr,
    const float* __restrict__ lemb, const float* __restrict__ remb,
    const float* __restrict__ d2w, const float* __restrict__ d2b,
    float* __restrict__ Y, int nrows) {
    constexpr int BM = 64;
    constexpr int BN = 2 * TC * 16;
    constexpr int CT = OUT / BN;
    constexpr int KT = SAGE ? 2 * K : K;
    constexpr int QX = BK / 4;
    constexpr int ST = BK + 4;
    constexpr int RX = (BM * QX + NB - 1) / NB;
    constexpr int RW = (BN * QX + NB - 1) / NB;
    __shared__ alignas(16) _Float16 Xhi[BM][ST];
    __shared__ alignas(16) _Float16 Xlo[BM][ST];
    __shared__ alignas(16) _Float16 Whi[BN][ST];
    __shared__ alignas(16) _Float16 Wlo[BN][ST];

    const int t = threadIdx.x;
    const int lane = t & 63;
    const int wave = t >> 6;
    const int lm = lane & 15, lg = lane >> 4;
    const int wm = (wave >> 1) * 32;
    const int wn = (wave & 1) * (TC * 16);

    const int bid = blockIdx.x;
    const int rowBase = (bid / CT) * BM;
    const int colTile = bid % CT;
    const int colBase = colTile * BN;

    float4 xreg[RX], wreg[RW];

    // issue global loads for k-step k0 into registers
    auto loadstep = [&](int k0) {
        const bool isG = SAGE && (k0 >= K);
        const float* __restrict__ Xp = isG ? G : X;
        const float* __restrict__ Wp = isG ? Wg : Wx;
        const int kl = isG ? (k0 - K) : k0;
#pragma unroll
        for (int rr = 0; rr < RX; ++rr) {
            int v = t + rr * NB;
            if (v < BM * QX) {
                int q = v % QX, m = v / QX;
                int r = rowBase + m;
                float4 f = {0.f, 0.f, 0.f, 0.f};
                if (r < nrows) {
                    if (EMB) {
                        int kk = kl + 4 * q;
                        if (kk < 64) {
                            int l = kk >> 4, c = kk & 15;
                            f = *reinterpret_cast<const float4*>(
                                &lemb[(size_t)xl[r * 4 + l] * 16 + c]);
                        } else {
                            f = *reinterpret_cast<const float4*>(
                                &remb[(size_t)xr[r] * 16 + (kk - 64)]);
                        }
                    } else {
                        f = *reinterpret_cast<const float4*>(
                            &Xp[(size_t)r * K + kl + 4 * q]);
                    }
                }
                xreg[rr] = f;
            }
        }
#pragma unroll
        for (int rr = 0; rr < RW; ++rr) {
            int v = t + rr * NB;
            if (v < BN * QX) {
                int q = v % QX, n = v / QX;
                wreg[rr] = *reinterpret_cast<const float4*>(
                    &Wp[(size_t)(colBase + n) * K + kl + 4 * q]);
            }
        }
    };

    // convert + write current registers into LDS
    auto storestep = [&]() {
#pragma unroll
        for (int rr = 0; rr < RX; ++rr) {
            int v = t + rr * NB;
            if (v < BM * QX) {
                int q = v % QX, m = v / QX;
                f16x4 hi, lo;
                cvt_split(xreg[rr], hi, lo);
                *reinterpret_cast<f16x4*>(&Xhi[m][4 * q]) = hi;
                *reinterpret_cast<f16x4*>(&Xlo[m][4 * q]) = lo;
            }
        }
#pragma unroll
        for (int rr = 0; rr < RW; ++rr) {
            int v = t + rr * NB;
            if (v < BN * QX) {
                int q = v % QX, n = v / QX;
                f16x4 hi, lo;
                cvt_split(wreg[rr], hi, lo);
                *reinterpret_cast<f16x4*>(&Whi[n][4 * q]) = hi;
                *reinterpret_cast<f16x4*>(&Wlo[n][4 * q]) = lo;
            }
        }
    };

    f32x4 acc[2][TC];
#pragma unroll
    for (int tr = 0; tr < 2; ++tr)
#pragma unroll
        for (int tc = 0; tc < TC; ++tc) acc[tr][tc] = (f32x4){0.f, 0.f, 0.f, 0.f};

    loadstep(0);
    for (int k0 = 0; k0 < KT; k0 += BK) {
        if (k0 > 0) __syncthreads();        // prev MFMA done; LDS reusable
        storestep();
        __syncthreads();                    // LDS tiles ready
        if (k0 + BK < KT) loadstep(k0 + BK);  // fly under the MFMAs below

#pragma unroll
        for (int g = 0; g < BK / 16; ++g) {
            f16x4 ah[2], al[2], bh[TC], bl[TC];
#pragma unroll
            for (int tr = 0; tr < 2; ++tr) {
                ah[tr] = *reinterpret_cast<const f16x4*>(
                    &Xhi[wm + tr * 16 + lm][g * 16 + 4 * lg]);
                al[tr] = *reinterpret_cast<const f16x4*>(
                    &Xlo[wm + tr * 16 + lm][g * 16 + 4 * lg]);
            }
#pragma unroll
            for (int tc = 0; tc < TC; ++tc) {
                bh[tc] = *reinterpret_cast<const f16x4*>(
                    &Whi[wn + tc * 16 + lm][g * 16 + 4 * lg]);
                bl[tc] = *reinterpret_cast<const f16x4*>(
                    &Wlo[wn + tc * 16 + lm][g * 16 + 4 * lg]);
            }
#pragma unroll
            for (int tr = 0; tr < 2; ++tr)
#pragma unroll
                for (int tc = 0; tc < TC; ++tc) {
                    acc[tr][tc] = __builtin_amdgcn_mfma_f32_16x16x16f16(
                        ah[tr], bh[tc], acc[tr][tc], 0, 0, 0);
                    acc[tr][tc] = __builtin_amdgcn_mfma_f32_16x16x16f16(
                        ah[tr], bl[tc], acc[tr][tc], 0, 0, 0);
                    acc[tr][tc] = __builtin_amdgcn_mfma_f32_16x16x16f16(
                        al[tr], bh[tc], acc[tr][tc], 0, 0, 0);
                }
        }
    }

    if (!FDOT) {
#pragma unroll
        for (int tr = 0; tr < 2; ++tr)
#pragma unroll
            for (int tc = 0; tc < TC; ++tc) {
                int c = colBase + wn + tc * 16 + lm;
#pragma unroll
                for (int j = 0; j < 4; ++j) {
                    int r = rowBase + wm + tr * 16 + 4 * lg + j;
                    if (r >= nrows) continue;
                    float v = acc[tr][tc][j] + bias[c];
                    if (RELU) v = fmaxf(v, 0.f);
                    Y[(size_t)r * OUT + c] = v;
                }
            }
    } else {
#pragma unroll
        for (int tr = 0; tr < 2; ++tr) {
            float p[4] = {0.f, 0.f, 0.f, 0.f};
#pragma unroll
            for (int tc = 0; tc < TC; ++tc) {
                int c = colBase + wn + tc * 16 + lm;
                float bv = bias[c];
                float dw = d2w[c];
#pragma unroll
                for (int j = 0; j < 4; ++j) {
                    float v = fmaxf(acc[tr][tc][j] + bv, 0.f);
                    p[j] += v * dw;
                }
            }
#pragma unroll
            for (int j = 0; j < 4; ++j) {
                float s = p[j];
#pragma unroll
                for (int off = 1; off < 16; off <<= 1) s += __shfl_xor(s, off);
                int r = rowBase + wm + tr * 16 + 4 * lg + j;
                if (lm == 0 && r < nrows) {
                    float extra = (colTile == 0 && wn == 0) ? d2b[0] : 0.f;
                    atomicAdd(&Y[r], s + extra);
                }
            }
        }
    }
}

// ---------------------------------------------------------------------------
extern "C" void kernel_launch(void* const* d_in, const int* in_sizes, int n_in,
                              void* d_out, int out_size, void* d_ws, size_t ws_size,
                              hipStream_t stream) {
    const int*   x_layout = (const int*)d_in[0];
    const int*   x_role   = (const int*)d_in[1];
    const int*   ei       = (const int*)d_in[2];
    const float* lemb     = (const float*)d_in[3];
    const float* remb     = (const float*)d_in[4];
    const float* lin_W    = (const float*)d_in[5];
    const float* lin_b    = (const float*)d_in[6];
    const float* c0_lW    = (const float*)d_in[7];
    const float* c0_lb    = (const float*)d_in[8];
    const float* c0_rW    = (const float*)d_in[9];
    const float* c1_lW    = (const float*)d_in[10];
    const float* c1_lb    = (const float*)d_in[11];
    const float* c1_rW    = (const float*)d_in[12];
    const float* c2_lW    = (const float*)d_in[13];
    const float* c2_lb    = (const float*)d_in[14];
    const float* c2_rW    = (const float*)d_in[15];
    const float* d0_W     = (const float*)d_in[16];
    const float* d0_b     = (const float*)d_in[17];
    const float* d1_W     = (const float*)d_in[18];
    const float* d1_b     = (const float*)d_in[19];
    const float* d2_W     = (const float*)d_in[20];
    const float* d2_b     = (const float*)d_in[21];

    const int N = in_sizes[1];
    const int E = in_sizes[2] / 2;
    const int* src = ei;
    const int* dst = ei + E;

    // workspace (4-byte elems):
    //   R0 (256N): early = [rowptr(N+1)|cursor(N)|col(E)|part(64)]; late = H0
    //   then A(96N) | B(96N) | C(96N)
    float* ws     = (float*)d_ws;
    float* H0     = ws;
    int*   rowptr = (int*)d_ws;
    int*   cursor = rowptr + (N + 1);
    int*   col    = cursor + N;
    int*   part   = col + E;
    float* A      = ws + (size_t)256 * N;
    float* B      = A + (size_t)96 * N;
    float* C      = B + (size_t)96 * N;

    const dim3 blk(NB);
    const int rt64 = (N + 63) / 64;
    const int nbScan = (N + 2047) / 2048;
    const dim3 gE((E + NB - 1) / NB);
    const dim3 gGather(((size_t)N * 24 + NB - 1) / NB);

    // ---- CSR build (multi-block scan) ----
    hipMemsetAsync(cursor, 0, (size_t)N * sizeof(int), stream);
    count_int_kernel<<<gE, blk, 0, stream>>>(dst, cursor, E);
    scan_part1<<<dim3(nbScan), blk, 0, stream>>>(cursor, part, N);
    scan_part2<<<dim3(1), dim3(64), 0, stream>>>(part, rowptr, nbScan, N);
    scan_part3<<<dim3(nbScan), blk, 0, stream>>>(cursor, part, rowptr, cursor, N);
    fill_csr_kernel<<<gE, blk, 0, stream>>>(src, dst, cursor, col, E);

    // ---- embed + lin -> A (embedding fused; K=80 -> BK=16) ----
    gemm_mfma<80, 96, 3, 16, false, false, true, false>
        <<<dim3(rt64), blk, 0, stream>>>(
        nullptr, nullptr, lin_W, nullptr, lin_b,
        x_layout, x_role, lemb, remb, nullptr, nullptr, A, N);

    // ---- layer 0: A -> C ----
    gather_mean_kernel<<<gGather, blk, 0, stream>>>(A, rowptr, col, B, N);
    gemm_mfma<96, 96, 3, 32, true, true, false, false>
        <<<dim3(rt64), blk, 0, stream>>>(
        A, B, c0_rW, c0_lW, c0_lb, nullptr, nullptr, nullptr, nullptr,
        nullptr, nullptr, C, N);

    // ---- layer 1: C -> A ----
    gather_mean_kernel<<<gGather, blk, 0, stream>>>(C, rowptr, col, B, N);
    gemm_mfma<96, 96, 3, 32, true, true, false, false>
        <<<dim3(rt64), blk, 0, stream>>>(
        C, B, c1_rW, c1_lW, c1_lb, nullptr, nullptr, nullptr, nullptr,
        nullptr, nullptr, A, N);

    // ---- layer 2: A -> C ----
    gather_mean_kernel<<<gGather, blk, 0, stream>>>(A, rowptr, col, B, N);
    gemm_mfma<96, 96, 3, 32, true, true, false, false>
        <<<dim3(rt64), blk, 0, stream>>>(
        A, B, c2_rW, c2_lW, c2_lb, nullptr, nullptr, nullptr, nullptr,
        nullptr, nullptr, C, N);

    // ---- head: d0 (C -> H0), then d1+d2 fused (H0 -> out) ----
    gemm_mfma<96, 256, 4, 32, true, false, false, false>
        <<<dim3(rt64 * 2), blk, 0, stream>>>(
        C, nullptr, d0_W, nullptr, d0_b, nullptr, nullptr, nullptr, nullptr,
        nullptr, nullptr, H0, N);

    hipMemsetAsync(d_out, 0, (size_t)N * sizeof(float), stream);
    gemm_mfma<256, 256, 4, 32, true, false, false, true>
        <<<dim3(rt64 * 2), blk, 0, stream>>>(
        H0, nullptr, d1_W, nullptr, d1_b, nullptr, nullptr, nullptr, nullptr,
        d2_W, d2_b, (float*)d_out, N);
}